// Round 9
// baseline (501.158 us; speedup 1.0000x reference)
//
#include <hip/hip_runtime.h>
#include <hip/hip_fp16.h>

// UniversalGRU: 2-layer GRU (B=2048, T=512, D=1, H=64) + FC(64->1).
// R9 = R7 (layer-skewed lockstep, 256 blocks x 512 thr, 1 barrier/t) with:
//  (a) MFMA rebalance: L0 waves also compute X1(t-1) = Wih1*hA(t-1) (+bias)
//      and publish f32 preacts in C-layout to Pbuf; L1 waves (now at skew
//      t-2) read them as per-lane float2 -- L1's MFMA chain 12->6, no hA
//      reads, no Wih1 frags, 4->3 bpermutes. Barrier convergence tightens.
//  (b) xbuf transposed to [t][8]: per-step x reads become same-address
//      LDS broadcasts (was 8/16-way bank conflict on stride-513).

#define T_LEN 512

typedef float          f32x4 __attribute__((ext_vector_type(4)));
typedef __bf16         bf16x8 __attribute__((ext_vector_type(8)));
typedef unsigned short us8   __attribute__((ext_vector_type(8)));
typedef unsigned short ushort_t;

__device__ __forceinline__ float bf2f(ushort_t b){
    unsigned int u = ((unsigned int)b) << 16;
    return __uint_as_float(u);
}
__device__ __forceinline__ ushort_t f2bf(float f){
    unsigned int u = __float_as_uint(f);
    u = (u + 0x7FFFu + ((u >> 16) & 1u)) >> 16;   // RNE
    return (ushort_t)u;
}
__device__ __forceinline__ float ld_any(const void* p, int i, bool f32){
    return f32 ? ((const float*)p)[i] : bf2f(((const ushort_t*)p)[i]);
}
__device__ __forceinline__ float sigm(float x){
    float e = __expf(-x);
    return __fdividef(1.0f, 1.0f + e);
}
__device__ __forceinline__ float tanh_f(float x){
    float e = __expf(2.0f * x);
    return fmaf(-2.0f, __fdividef(1.0f, e + 1.0f), 1.0f);
}
__device__ __forceinline__ f32x4 mfma16(bf16x8 a, bf16x8 b, f32x4 c){
    return __builtin_amdgcn_mfma_f32_16x16x32_bf16(a, b, c, 0, 0, 0);
}
__device__ __forceinline__ float pack2(float a, float b){
    __half2 h = __floats2half2_rn(a, b);
    return __builtin_bit_cast(float, h);
}
__device__ __forceinline__ float2 unpack2(float p){
    __half2 h = __builtin_bit_cast(__half2, p);
    return __half22float2(h);
}
__device__ __forceinline__ bf16x8 mk_frag(const void* W, int n, int kb, bool f32){
    us8 tmp;
    #pragma unroll
    for (int j = 0; j < 8; ++j){
        tmp[j] = f32 ? f2bf(((const float*)W)[n * 64 + kb + j])
                     : ((const ushort_t*)W)[n * 64 + kb + j];
    }
    return __builtin_bit_cast(bf16x8, tmp);
}

__global__ __launch_bounds__(512, 2) void gru_fused(
    const void* __restrict__ xv,
    const void* __restrict__ Wih0, const void* __restrict__ Whh0,
    const void* __restrict__ bih0, const void* __restrict__ bhh0,
    const void* __restrict__ Wih1, const void* __restrict__ Whh1,
    const void* __restrict__ bih1, const void* __restrict__ bhh1,
    const void* __restrict__ Wfc,  const void* __restrict__ bfc,
    void* __restrict__ outv)
{
    __shared__ float    xbuf[T_LEN * 8];         // transposed: [t][row]
    __shared__ ushort_t hbufA[2][16 * 72];       // hA, A-layout bf16, dbuf
    __shared__ ushort_t hbufB[2][16 * 72];       // hB
    __shared__ float    Pbuf[2][3][64][8];       // X1 preacts [slot][gate][col][row]
    __shared__ float    outb[8][68];

    const int tid  = threadIdx.x;
    const int wv   = tid >> 6;                   // 0..7
    const bool isL1 = (wv >= 4);
    const int w    = wv & 3;                     // n-tile group within role
    const int c    = tid & 15;
    const int q    = (tid >> 4) & 3;
    const int ih   = w * 16 + c;                 // owned h-col
    const int hi   = q >> 1;
    const int mrow = (q & 1) * 4 + hi * 2;       // first of lane's 2 real rows
    const long row0 = (long)blockIdx.x * 8;

    // dtype detection (uniform)
    bool f32 = false;
    {
        const ushort_t* xs = (const ushort_t*)xv;
        for (int j = 0; j < 64; ++j){
            int e = (xs[2 * j] >> 7) & 0xFF;
            if (e > 150) f32 = true;
        }
    }

    // zero h double-buffers
    {
        ushort_t* pa = &hbufA[0][0];
        ushort_t* pb = &hbufB[0][0];
        for (int k = tid; k < 2 * 16 * 72; k += 512){ pa[k] = 0; pb[k] = 0; }
    }
    // stage x transposed: xbuf[t*8 + r] (one-time scatter; loop reads broadcast)
    {
        const int r = wv;
        const int g = tid & 63;
        if (f32){
            const f32x4* src = (const f32x4*)((const float*)xv + (row0 + r) * T_LEN);
            #pragma unroll
            for (int it = 0; it < 2; ++it){
                f32x4 v = src[g + 64 * it];
                #pragma unroll
                for (int j = 0; j < 4; ++j)
                    xbuf[((g + 64 * it) * 4 + j) * 8 + r] = v[j];
            }
        } else {
            const us8* src = (const us8*)((const ushort_t*)xv + (row0 + r) * T_LEN);
            us8 v = src[g];
            #pragma unroll
            for (int j = 0; j < 8; ++j)
                xbuf[(g * 8 + j) * 8 + r] = bf2f(v[j]);
        }
    }

    // Weights. B[k][n]=W[n][k]; lane: n = 64*g + ih, k = 32*f + 8*q + j.
    bf16x8 wA[3][2];                 // L0: Whh0 ; L1: Whh1
    bf16x8 wI[3][2];                 // L0 only: Wih1
    float sxr = 0.f, sxz = 0.f, sxn = 0.f;
    float b0r = 0.f, b0z = 0.f, b0nx = 0.f, b0nh = 0.f;
    float bx1r = 0.f, bx1z = 0.f, bx1nx = 0.f;   // L1 biases carried in X1
    float b1nh = 0.f;                            // L1's HN bias
    const int kb0 = q * 8;
    if (!isL1){
        #pragma unroll
        for (int g = 0; g < 3; ++g){
            const int n = g * 64 + ih;
            #pragma unroll
            for (int f = 0; f < 2; ++f){
                wA[g][f] = mk_frag(Whh0, n, f * 32 + kb0, f32);
                wI[g][f] = mk_frag(Wih1, n, f * 32 + kb0, f32);
            }
        }
        sxr  = ld_any(Wih0, ih, f32);
        sxz  = ld_any(Wih0, 64 + ih, f32);
        sxn  = ld_any(Wih0, 128 + ih, f32);
        b0r  = ld_any(bih0, ih, f32)       + ld_any(bhh0, ih, f32);
        b0z  = ld_any(bih0, 64 + ih, f32)  + ld_any(bhh0, 64 + ih, f32);
        b0nx = ld_any(bih0, 128 + ih, f32);
        b0nh = ld_any(bhh0, 128 + ih, f32);
        bx1r  = ld_any(bih1, ih, f32)      + ld_any(bhh1, ih, f32);
        bx1z  = ld_any(bih1, 64 + ih, f32) + ld_any(bhh1, 64 + ih, f32);
        bx1nx = ld_any(bih1, 128 + ih, f32);
    } else {
        #pragma unroll
        for (int g = 0; g < 3; ++g){
            const int n = g * 64 + ih;
            #pragma unroll
            for (int f = 0; f < 2; ++f)
                wA[g][f] = mk_frag(Whh1, n, f * 32 + kb0, f32);
        }
        b1nh = ld_any(bhh1, 128 + ih, f32);
    }

    float h2[2] = {0.f, 0.f};
    const int aoff = c * 72 + q * 8;             // A-frag base

    // L1 step body: consume X1 preacts (slot ps), own hB(s-1) (slot ps), emit hB(s).
    auto l1_step = [&](int ps, bool to_out){
        const float* pb = &Pbuf[ps][0][0][0];
        float2 pR = *(const float2*)(pb + 0 * 512 + ih * 8 + mrow);
        float2 pZ = *(const float2*)(pb + 1 * 512 + ih * 8 + mrow);
        float2 pN = *(const float2*)(pb + 2 * 512 + ih * 8 + mrow);
        us8 b0u = *(const us8*)&hbufB[ps][aoff];
        us8 b1u = *(const us8*)&hbufB[ps][aoff + 32];
        bf16x8 hb0 = __builtin_bit_cast(bf16x8, b0u);
        bf16x8 hb1 = __builtin_bit_cast(bf16x8, b1u);
        f32x4 hR = {0.f, 0.f, 0.f, 0.f};
        f32x4 hZ = {0.f, 0.f, 0.f, 0.f};
        f32x4 hN = {b1nh, b1nh, b1nh, b1nh};
        hR = mfma16(hb0, wA[0][0], hR); hR = mfma16(hb1, wA[0][1], hR);
        hZ = mfma16(hb0, wA[1][0], hZ); hZ = mfma16(hb1, wA[1][1], hZ);
        hN = mfma16(hb0, wA[2][0], hN); hN = mfma16(hb1, wA[2][1], hN);
        float2 uR = unpack2(__shfl_up(pack2(hR[2], hR[3]), 32));
        float2 uZ = unpack2(__shfl_up(pack2(hZ[2], hZ[3]), 32));
        float2 uN = unpack2(__shfl_up(pack2(hN[2], hN[3]), 32));
        float gR[2] = { hi ? uR.x : hR[0], hi ? uR.y : hR[1] };
        float gZ[2] = { hi ? uZ.x : hZ[0], hi ? uZ.y : hZ[1] };
        float gN[2] = { hi ? uN.x : hN[0], hi ? uN.y : hN[1] };
        float pRa[2] = {pR.x, pR.y}, pZa[2] = {pZ.x, pZ.y}, pNa[2] = {pN.x, pN.y};
        #pragma unroll
        for (int j = 0; j < 2; ++j){
            float rg = sigm(pRa[j] + gR[j]);
            float zg = sigm(pZa[j] + gZ[j]);
            float ng = tanh_f(pNa[j] + rg * gN[j]);
            h2[j] = ng + zg * (h2[j] - ng);
            if (to_out) outb[mrow + j][ih] = h2[j];
            else        hbufB[ps ^ 1][(mrow + j) * 72 + ih] = f2bf(h2[j]);
        }
    };
    // L0 X1 publisher: X1 = Wih1 * hA + b1, from frags (a0,a1), into Pbuf[slot].
    auto l0_x1 = [&](bf16x8 a0, bf16x8 a1, int slot){
        f32x4 xR = {bx1r, bx1r, bx1r, bx1r};
        f32x4 xZ = {bx1z, bx1z, bx1z, bx1z};
        f32x4 xN = {bx1nx, bx1nx, bx1nx, bx1nx};
        xR = mfma16(a0, wI[0][0], xR); xR = mfma16(a1, wI[0][1], xR);
        xZ = mfma16(a0, wI[1][0], xZ); xZ = mfma16(a1, wI[1][1], xZ);
        xN = mfma16(a0, wI[2][0], xN); xN = mfma16(a1, wI[2][1], xN);
        if (q < 2){
            *(f32x4*)&Pbuf[slot][0][ih][q * 4] = xR;
            *(f32x4*)&Pbuf[slot][1][ih][q * 4] = xZ;
            *(f32x4*)&Pbuf[slot][2][ih][q * 4] = xN;
        }
    };

    __syncthreads();

    for (int t = 0; t < T_LEN; ++t){
        const int p = t & 1;
        if (!isL1){
            // L0 step t: hA(t) = GRU0(x(t), hA(t-1)); publish X1(t-1).
            us8 a0u = *(const us8*)&hbufA[p][aoff];
            us8 a1u = *(const us8*)&hbufA[p][aoff + 32];
            bf16x8 a0 = __builtin_bit_cast(bf16x8, a0u);
            bf16x8 a1 = __builtin_bit_cast(bf16x8, a1u);
            f32x4 aR = {b0r, b0r, b0r, b0r};
            f32x4 aZ = {b0z, b0z, b0z, b0z};
            f32x4 aN = {b0nh, b0nh, b0nh, b0nh};
            aR = mfma16(a0, wA[0][0], aR); aR = mfma16(a1, wA[0][1], aR);
            aZ = mfma16(a0, wA[1][0], aZ); aZ = mfma16(a1, wA[1][1], aZ);
            aN = mfma16(a0, wA[2][0], aN); aN = mfma16(a1, wA[2][1], aN);
            l0_x1(a0, a1, p);                       // X1(t-1) -> Pbuf[t&1]
            float2 uR = unpack2(__shfl_up(pack2(aR[2], aR[3]), 32));
            float2 uZ = unpack2(__shfl_up(pack2(aZ[2], aZ[3]), 32));
            float2 uN = unpack2(__shfl_up(pack2(aN[2], aN[3]), 32));
            float gR[2] = { hi ? uR.x : aR[0], hi ? uR.y : aR[1] };
            float gZ[2] = { hi ? uZ.x : aZ[0], hi ? uZ.y : aZ[1] };
            float gN[2] = { hi ? uN.x : aN[0], hi ? uN.y : aN[1] };
            float2 xm2 = *(const float2*)&xbuf[t * 8 + mrow];   // broadcast read
            float xm[2] = {xm2.x, xm2.y};
            #pragma unroll
            for (int j = 0; j < 2; ++j){
                float rg = sigm(fmaf(xm[j], sxr, gR[j]));
                float zg = sigm(fmaf(xm[j], sxz, gZ[j]));
                float ng = tanh_f(fmaf(xm[j], sxn, b0nx) + rg * gN[j]);
                h2[j] = ng + zg * (h2[j] - ng);
                hbufA[p ^ 1][(mrow + j) * 72 + ih] = f2bf(h2[j]);
            }
        } else if (t >= 2){
            // L1 step t: hB(t-2) from X1(t-2) [Pbuf[p^1]] and hB(t-3) [hbufB[p^1]]
            l1_step(p ^ 1, false);
        }
        __syncthreads();
    }

    // Epilogue: publish X1(511), then L1 runs s=510, s=511.
    if (!isL1){
        us8 a0u = *(const us8*)&hbufA[0][aoff];      // hA(511)
        us8 a1u = *(const us8*)&hbufA[0][aoff + 32];
        l0_x1(__builtin_bit_cast(bf16x8, a0u), __builtin_bit_cast(bf16x8, a1u), 0);
    }
    __syncthreads();                                 // E1
    if (isL1) l1_step(1, false);                     // s=510: X1(510), hB(509)
    __syncthreads();                                 // E2
    if (isL1) l1_step(0, true);                      // s=511: X1(511), hB(510) -> outb
    __syncthreads();                                 // E3

    // FC: out[row] = sum_i Wfc[i]*h2[row][i] + bfc
    if (tid < 8){
        float s = ld_any(bfc, 0, f32);
        for (int i2 = 0; i2 < 64; ++i2) s = fmaf(ld_any(Wfc, i2, f32), outb[tid][i2], s);
        if (f32) ((float*)outv)[row0 + tid] = s;
        else     ((ushort_t*)outv)[row0 + tid] = f2bf(s);
    }
}

extern "C" void kernel_launch(void* const* d_in, const int* in_sizes, int n_in,
                              void* d_out, int out_size, void* d_ws, size_t ws_size,
                              hipStream_t stream)
{
    (void)in_sizes; (void)n_in; (void)d_ws; (void)ws_size;
    const int B = out_size;            // O = 1 -> out_size == batch
    const int nblk = B / 8;            // 256 blocks
    gru_fused<<<nblk, 512, 0, stream>>>(
        d_in[0],
        d_in[1], d_in[2], d_in[3], d_in[4],
        d_in[5], d_in[6], d_in[7], d_in[8],
        d_in[9], d_in[10],
        d_out);
}

// Round 11
// 463.483 us; speedup vs baseline: 1.0813x; 1.0813x over previous
//
#include <hip/hip_runtime.h>
#include <hip/hip_fp16.h>

// UniversalGRU: 2-layer GRU (B=2048, T=512, D=1, H=64) + FC(64->1).
// R11 = R10 with the compile fix (manual bf16 pair store; __hip_bfloat162
// is not trivially copyable -> no bit_cast). Hypothesis under test:
//  (a) hbuf row stride 72 -> 76 shorts: the b128 A-frag reads previously
//      mapped 8 lanes onto each 4-bank window (start bank 4*((c+q)%8)) ->
//      8-way serialization = the 1.27e7 SQ_LDS_BANK_CONFLICT. Stride 76
//      gives start banks (6c+4q)%32 -> <=2-way (free per m136).
//  (b) #pragma unroll 2 on the t-loop.
// Base: layer-skewed lockstep, 256 blocks x 512 thr, 1 barrier/t,
// f16x2-packed single-shfl gate redistribution.

#define T_LEN 512
#define ROWS  8
#define XPAD  513
#define STR   76          // hbuf row stride in shorts (was 72)

typedef float          f32x4 __attribute__((ext_vector_type(4)));
typedef __bf16         bf16x8 __attribute__((ext_vector_type(8)));
typedef unsigned short us8   __attribute__((ext_vector_type(8)));
typedef unsigned short ushort_t;

__device__ __forceinline__ float bf2f(ushort_t b){
    unsigned int u = ((unsigned int)b) << 16;
    return __uint_as_float(u);
}
__device__ __forceinline__ ushort_t f2bf(float f){
    unsigned int u = __float_as_uint(f);
    u = (u + 0x7FFFu + ((u >> 16) & 1u)) >> 16;   // RNE
    return (ushort_t)u;
}
__device__ __forceinline__ float ld_any(const void* p, int i, bool f32){
    return f32 ? ((const float*)p)[i] : bf2f(((const ushort_t*)p)[i]);
}
__device__ __forceinline__ float sigm(float x){
    float e = __expf(-x);
    return __fdividef(1.0f, 1.0f + e);
}
__device__ __forceinline__ float tanh_f(float x){
    float e = __expf(2.0f * x);
    return fmaf(-2.0f, __fdividef(1.0f, e + 1.0f), 1.0f);
}
__device__ __forceinline__ f32x4 mfma16(bf16x8 a, bf16x8 b, f32x4 c){
    return __builtin_amdgcn_mfma_f32_16x16x32_bf16(a, b, c, 0, 0, 0);
}
// f16x2 pack/unpack for single-shfl redistribution of two preact rows.
__device__ __forceinline__ float pack2(float a, float b){
    __half2 h = __floats2half2_rn(a, b);          // v_cvt_pkrtz
    return __builtin_bit_cast(float, h);
}
__device__ __forceinline__ float2 unpack2(float p){
    __half2 h = __builtin_bit_cast(__half2, p);
    return __half22float2(h);
}
// Build a B-fragment (8 contiguous k's of W[n][k]) from either dtype.
__device__ __forceinline__ bf16x8 mk_frag(const void* W, int n, int kb, bool f32){
    us8 tmp;
    #pragma unroll
    for (int j = 0; j < 8; ++j){
        tmp[j] = f32 ? f2bf(((const float*)W)[n * 64 + kb + j])
                     : ((const ushort_t*)W)[n * 64 + kb + j];
    }
    return __builtin_bit_cast(bf16x8, tmp);
}

__global__ __launch_bounds__(512, 2) void gru_fused(
    const void* __restrict__ xv,
    const void* __restrict__ Wih0, const void* __restrict__ Whh0,
    const void* __restrict__ bih0, const void* __restrict__ bhh0,
    const void* __restrict__ Wih1, const void* __restrict__ Whh1,
    const void* __restrict__ bih1, const void* __restrict__ bhh1,
    const void* __restrict__ Wfc,  const void* __restrict__ bfc,
    void* __restrict__ outv)
{
    __shared__ float    xbuf[ROWS * XPAD];       // staged x, padded stride
    __shared__ ushort_t hbufA[2][16 * STR];      // layer-0 h, A-layout bf16, dbuf
    __shared__ ushort_t hbufB[2][16 * STR];      // layer-1 h
    __shared__ float    outb[ROWS][68];          // final h2 for FC

    const int tid  = threadIdx.x;
    const int wv   = tid >> 6;                   // 0..7
    const bool isL1 = (wv >= 4);
    const int w    = wv & 3;                     // n-tile group within role
    const int c    = tid & 15;                   // MFMA col-within-tile
    const int q    = (tid >> 4) & 3;             // quad
    const int ih   = w * 16 + c;                 // h-col this lane's gates own
    const int hi   = q >> 1;                     // upper-half-wave flag
    const int mrow = (q & 1) * 4 + hi * 2;       // first of this lane's 2 REAL rows
    const long row0 = (long)blockIdx.x * ROWS;

    // dtype detection (uniform): fp32 misread as bf16 -> mantissa-noise
    // exponents in even ushort slots; true bf16 never exceeds exp 150.
    bool f32 = false;
    {
        const ushort_t* xs = (const ushort_t*)xv;
        for (int j = 0; j < 64; ++j){
            int e = (xs[2 * j] >> 7) & 0xFF;
            if (e > 150) f32 = true;
        }
    }

    // zero h double-buffers (h0 = 0; also hB(-1)=0 for the skewed start)
    {
        ushort_t* pa = &hbufA[0][0];
        ushort_t* pb = &hbufB[0][0];
        for (int k = tid; k < 2 * 16 * STR; k += 512){ pa[k] = 0; pb[k] = 0; }
    }
    // stage x: wave wv loads row wv (8 rows x 512), coalesced
    {
        const int r = wv;
        const int g = tid & 63;
        if (f32){
            const f32x4* src = (const f32x4*)((const float*)xv + (row0 + r) * T_LEN);
            #pragma unroll
            for (int it = 0; it < 2; ++it){
                f32x4 v = src[g + 64 * it];
                #pragma unroll
                for (int j = 0; j < 4; ++j)
                    xbuf[r * XPAD + (g + 64 * it) * 4 + j] = v[j];
            }
        } else {
            const us8* src = (const us8*)((const ushort_t*)xv + (row0 + r) * T_LEN);
            us8 v = src[g];
            #pragma unroll
            for (int j = 0; j < 8; ++j)
                xbuf[r * XPAD + g * 8 + j] = bf2f(v[j]);
        }
    }

    // Role-specific weights. B[k][n]=W[n][k]; lane: n = 64*g + ih, k = 32*f+8*q+j.
    bf16x8 wA[3][2], wB[3][2];                   // L0: wA=Whh0. L1: wA=Wih1, wB=Whh1.
    float sxr = 0.f, sxz = 0.f, sxn = 0.f;       // L0 scalar x-weights
    float br, bz, bnx, bnh;
    if (!isL1){
        #pragma unroll
        for (int g = 0; g < 3; ++g){
            const int n = g * 64 + ih;
            #pragma unroll
            for (int f = 0; f < 2; ++f)
                wA[g][f] = mk_frag(Whh0, n, f * 32 + q * 8, f32);
        }
        sxr = ld_any(Wih0, ih, f32);
        sxz = ld_any(Wih0, 64 + ih, f32);
        sxn = ld_any(Wih0, 128 + ih, f32);
        br  = ld_any(bih0, ih, f32)       + ld_any(bhh0, ih, f32);
        bz  = ld_any(bih0, 64 + ih, f32)  + ld_any(bhh0, 64 + ih, f32);
        bnx = ld_any(bih0, 128 + ih, f32);
        bnh = ld_any(bhh0, 128 + ih, f32);
    } else {
        #pragma unroll
        for (int g = 0; g < 3; ++g){
            const int n = g * 64 + ih;
            #pragma unroll
            for (int f = 0; f < 2; ++f){
                wA[g][f] = mk_frag(Wih1, n, f * 32 + q * 8, f32);
                wB[g][f] = mk_frag(Whh1, n, f * 32 + q * 8, f32);
            }
        }
        br  = ld_any(bih1, ih, f32)       + ld_any(bhh1, ih, f32);
        bz  = ld_any(bih1, 64 + ih, f32)  + ld_any(bhh1, 64 + ih, f32);
        bnx = ld_any(bih1, 128 + ih, f32);
        bnh = ld_any(bhh1, 128 + ih, f32);
    }

    float h2[2] = {0.f, 0.f};          // fp32-carried h for this lane's 2 real rows
    const int aoff = c * STR + q * 8;  // A-frag base: A[m=c][k=8q(+32f)]

    __syncthreads();

    #pragma unroll 2
    for (int t = 0; t < T_LEN; ++t){
        const int p = t & 1;
        if (!isL1){
            // ---- layer 0, step t: hA(t) = GRU0(x(t), hA(t-1))
            us8 a0u = *(const us8*)&hbufA[p][aoff];
            us8 a1u = *(const us8*)&hbufA[p][aoff + 32];
            bf16x8 a0 = __builtin_bit_cast(bf16x8, a0u);
            bf16x8 a1 = __builtin_bit_cast(bf16x8, a1u);
            f32x4 aR = {br, br, br, br};
            f32x4 aZ = {bz, bz, bz, bz};
            f32x4 aN = {bnh, bnh, bnh, bnh};
            aR = mfma16(a0, wA[0][0], aR); aR = mfma16(a1, wA[0][1], aR);
            aZ = mfma16(a0, wA[1][0], aZ); aZ = mfma16(a1, wA[1][1], aZ);
            aN = mfma16(a0, wA[2][0], aN); aN = mfma16(a1, wA[2][1], aN);
            // single-shfl redistribution: regs(2,3) packed f16x2 -> lanes+32
            float2 uR = unpack2(__shfl_up(pack2(aR[2], aR[3]), 32));
            float2 uZ = unpack2(__shfl_up(pack2(aZ[2], aZ[3]), 32));
            float2 uN = unpack2(__shfl_up(pack2(aN[2], aN[3]), 32));
            float gR[2] = { hi ? uR.x : aR[0], hi ? uR.y : aR[1] };
            float gZ[2] = { hi ? uZ.x : aZ[0], hi ? uZ.y : aZ[1] };
            float gN[2] = { hi ? uN.x : aN[0], hi ? uN.y : aN[1] };
            float xm[2] = { xbuf[mrow * XPAD + t], xbuf[(mrow + 1) * XPAD + t] };
            #pragma unroll
            for (int j = 0; j < 2; ++j){
                float rg = sigm(fmaf(xm[j], sxr, gR[j]));
                float zg = sigm(fmaf(xm[j], sxz, gZ[j]));
                float ng = tanh_f(fmaf(xm[j], sxn, bnx) + rg * gN[j]);
                h2[j] = ng + zg * (h2[j] - ng);
                hbufA[p ^ 1][(mrow + j) * STR + ih] = f2bf(h2[j]);
            }
        } else if (t > 0){
            // ---- layer 1, step t-1: hB(t-1) = GRU1(hA(t-1), hB(t-2))
            us8 a0u = *(const us8*)&hbufA[p][aoff];        // hA(t-1)
            us8 a1u = *(const us8*)&hbufA[p][aoff + 32];
            us8 b0u = *(const us8*)&hbufB[p][aoff];        // hB(t-2)
            us8 b1u = *(const us8*)&hbufB[p][aoff + 32];
            bf16x8 a0 = __builtin_bit_cast(bf16x8, a0u);
            bf16x8 a1 = __builtin_bit_cast(bf16x8, a1u);
            bf16x8 b0 = __builtin_bit_cast(bf16x8, b0u);
            bf16x8 b1 = __builtin_bit_cast(bf16x8, b1u);
            f32x4 aR  = {br, br, br, br};
            f32x4 aZ  = {bz, bz, bz, bz};
            f32x4 aXn = {bnx, bnx, bnx, bnx};
            f32x4 aHn = {bnh, bnh, bnh, bnh};
            aR  = mfma16(a0, wA[0][0], aR);  aR  = mfma16(a1, wA[0][1], aR);
            aR  = mfma16(b0, wB[0][0], aR);  aR  = mfma16(b1, wB[0][1], aR);
            aZ  = mfma16(a0, wA[1][0], aZ);  aZ  = mfma16(a1, wA[1][1], aZ);
            aZ  = mfma16(b0, wB[1][0], aZ);  aZ  = mfma16(b1, wB[1][1], aZ);
            aXn = mfma16(a0, wA[2][0], aXn); aXn = mfma16(a1, wA[2][1], aXn);
            aHn = mfma16(b0, wB[2][0], aHn); aHn = mfma16(b1, wB[2][1], aHn);
            float2 uR = unpack2(__shfl_up(pack2(aR[2],  aR[3]),  32));
            float2 uZ = unpack2(__shfl_up(pack2(aZ[2],  aZ[3]),  32));
            float2 uX = unpack2(__shfl_up(pack2(aXn[2], aXn[3]), 32));
            float2 uN = unpack2(__shfl_up(pack2(aHn[2], aHn[3]), 32));
            float gR[2] = { hi ? uR.x : aR[0],  hi ? uR.y : aR[1] };
            float gZ[2] = { hi ? uZ.x : aZ[0],  hi ? uZ.y : aZ[1] };
            float gX[2] = { hi ? uX.x : aXn[0], hi ? uX.y : aXn[1] };
            float gN[2] = { hi ? uN.x : aHn[0], hi ? uN.y : aHn[1] };
            #pragma unroll
            for (int j = 0; j < 2; ++j){
                float rg = sigm(gR[j]);
                float zg = sigm(gZ[j]);
                float ng = tanh_f(gX[j] + rg * gN[j]);
                h2[j] = ng + zg * (h2[j] - ng);
                hbufB[p ^ 1][(mrow + j) * STR + ih] = f2bf(h2[j]);
            }
        }
        __syncthreads();
    }

    // Epilogue: L1 waves compute the final step hB(511) from hA(511), hB(510)
    // (both sit in buffer 0 after 512 iterations).
    if (isL1){
        us8 a0u = *(const us8*)&hbufA[0][aoff];
        us8 a1u = *(const us8*)&hbufA[0][aoff + 32];
        us8 b0u = *(const us8*)&hbufB[0][aoff];
        us8 b1u = *(const us8*)&hbufB[0][aoff + 32];
        bf16x8 a0 = __builtin_bit_cast(bf16x8, a0u);
        bf16x8 a1 = __builtin_bit_cast(bf16x8, a1u);
        bf16x8 b0 = __builtin_bit_cast(bf16x8, b0u);
        bf16x8 b1 = __builtin_bit_cast(bf16x8, b1u);
        f32x4 aR  = {br, br, br, br};
        f32x4 aZ  = {bz, bz, bz, bz};
        f32x4 aXn = {bnx, bnx, bnx, bnx};
        f32x4 aHn = {bnh, bnh, bnh, bnh};
        aR  = mfma16(a0, wA[0][0], aR);  aR  = mfma16(a1, wA[0][1], aR);
        aR  = mfma16(b0, wB[0][0], aR);  aR  = mfma16(b1, wB[0][1], aR);
        aZ  = mfma16(a0, wA[1][0], aZ);  aZ  = mfma16(a1, wA[1][1], aZ);
        aZ  = mfma16(b0, wB[1][0], aZ);  aZ  = mfma16(b1, wB[1][1], aZ);
        aXn = mfma16(a0, wA[2][0], aXn); aXn = mfma16(a1, wA[2][1], aXn);
        aHn = mfma16(b0, wB[2][0], aHn); aHn = mfma16(b1, wB[2][1], aHn);
        float2 uR = unpack2(__shfl_up(pack2(aR[2],  aR[3]),  32));
        float2 uZ = unpack2(__shfl_up(pack2(aZ[2],  aZ[3]),  32));
        float2 uX = unpack2(__shfl_up(pack2(aXn[2], aXn[3]), 32));
        float2 uN = unpack2(__shfl_up(pack2(aHn[2], aHn[3]), 32));
        float gR[2] = { hi ? uR.x : aR[0],  hi ? uR.y : aR[1] };
        float gZ[2] = { hi ? uZ.x : aZ[0],  hi ? uZ.y : aZ[1] };
        float gX[2] = { hi ? uX.x : aXn[0], hi ? uX.y : aXn[1] };
        float gN[2] = { hi ? uN.x : aHn[0], hi ? uN.y : aHn[1] };
        #pragma unroll
        for (int j = 0; j < 2; ++j){
            float rg = sigm(gR[j]);
            float zg = sigm(gZ[j]);
            float ng = tanh_f(gX[j] + rg * gN[j]);
            float hf = ng + zg * (h2[j] - ng);
            outb[mrow + j][ih] = hf;
        }
    }
    __syncthreads();

    // FC: out[row] = sum_i Wfc[i]*h2[row][i] + bfc
    if (tid < ROWS){
        float s = ld_any(bfc, 0, f32);
        for (int i2 = 0; i2 < 64; ++i2) s = fmaf(ld_any(Wfc, i2, f32), outb[tid][i2], s);
        if (f32) ((float*)outv)[row0 + tid] = s;
        else     ((ushort_t*)outv)[row0 + tid] = f2bf(s);
    }
}

extern "C" void kernel_launch(void* const* d_in, const int* in_sizes, int n_in,
                              void* d_out, int out_size, void* d_ws, size_t ws_size,
                              hipStream_t stream)
{
    (void)in_sizes; (void)n_in; (void)d_ws; (void)ws_size;
    const int B = out_size;            // O = 1 -> out_size == batch
    const int nblk = B / ROWS;         // 2048/8 = 256 blocks
    gru_fused<<<nblk, 512, 0, stream>>>(
        d_in[0],
        d_in[1], d_in[2], d_in[3], d_in[4],
        d_in[5], d_in[6], d_in[7], d_in[8],
        d_in[9], d_in[10],
        d_out);
}